// Round 6
// baseline (367.767 us; speedup 1.0000x reference)
//
#include <hip/hip_runtime.h>
#include <hip/hip_bf16.h>

typedef __attribute__((ext_vector_type(8))) short bf16x8;
typedef __attribute__((ext_vector_type(4))) float f32x4;

#define MFMA16(a, b, c) __builtin_amdgcn_mfma_f32_16x16x32_bf16(a, b, c, 0, 0, 0)

static __device__ __forceinline__ unsigned short f2bf(float f) {
  union { __hip_bfloat16 h; unsigned short u; } cv;
  cv.h = __float2bfloat16(f);
  return cv.u;
}

static __device__ __forceinline__ void gload16(const void* gptr, void* lptr) {
  __builtin_amdgcn_global_load_lds(
      (const __attribute__((address_space(1))) void*)gptr,
      (__attribute__((address_space(3))) void*)lptr, 16, 0, 0);
}

// ---------------- fused prep kernels ----------------

__global__ void conv_w_k(const float* __restrict__ qW1, const float* __restrict__ kW1,
                         const float* __restrict__ qW2, const float* __restrict__ kW2,
                         const float* __restrict__ vW, const float* __restrict__ wW,
                         __hip_bfloat16* __restrict__ dst) {
  int i = blockIdx.x * 256 + threadIdx.x;  // 0..655359
  const float* src; int off;
  if (i < 131072)      { src = qW1; off = i; }
  else if (i < 262144) { src = kW1; off = i - 131072; }
  else if (i < 327680) { src = qW2; off = i - 262144; }
  else if (i < 393216) { src = kW2; off = i - 327680; }
  else if (i < 524288) { src = vW;  off = i - 393216; }
  else                 { src = wW;  off = i - 524288; }
  dst[i] = __float2bfloat16(src[off]);
}

__global__ void bn_all_k(const float* __restrict__ qG1, const float* __restrict__ qB1, const float* __restrict__ qM1, const float* __restrict__ qV1,
                         const float* __restrict__ qG2, const float* __restrict__ qB2, const float* __restrict__ qM2, const float* __restrict__ qV2,
                         const float* __restrict__ kG1, const float* __restrict__ kB1, const float* __restrict__ kM1, const float* __restrict__ kV1,
                         const float* __restrict__ kG2, const float* __restrict__ kB2, const float* __restrict__ kM2, const float* __restrict__ kV2,
                         const float* __restrict__ wG, const float* __restrict__ wB, const float* __restrict__ wM, const float* __restrict__ wV,
                         float* __restrict__ base) {
  int bidx = blockIdx.x, tid = threadIdx.x;
  const float *g, *b, *m, *v; float *s, *t; int i;
  if (bidx == 0)      { g = qG1; b = qB1; m = qM1; v = qV1; s = base;        t = base + 256;  i = tid; }
  else if (bidx == 1) { g = qG2; b = qB2; m = qM2; v = qV2; s = base + 512;  t = base + 768;  i = tid; }
  else if (bidx == 2) { g = kG1; b = kB1; m = kM1; v = kV1; s = base + 1024; t = base + 1280; i = tid; }
  else if (bidx == 3) { g = kG2; b = kB2; m = kM2; v = kV2; s = base + 1536; t = base + 1792; i = tid; }
  else                { g = wG;  b = wB;  m = wM;  v = wV;  s = base + 2048; t = base + 2560; i = (bidx - 4) * 256 + tid; }
  float sv = g[i] * rsqrtf(v[i] + 1e-5f);
  s[i] = sv;
  t[i] = b[i] - m[i] * sv;
}

// x (B,512,4096) fp32 -> xT (B,4096,512) bf16
__global__ __launch_bounds__(256) void transpose_k(const float* __restrict__ x,
                                                   __hip_bfloat16* __restrict__ xT) {
  __shared__ float tile[64][65];
  const int n0 = blockIdx.x * 64, c0 = blockIdx.y * 64, b = blockIdx.z;
  const int tx = threadIdx.x, ty = threadIdx.y;
  const float* xp = x + ((size_t)(b * 512 + c0) * 4096) + n0;
#pragma unroll
  for (int i = 0; i < 16; ++i) {
    int c = ty + 4 * i;
    tile[c][tx] = xp[(size_t)c * 4096 + tx];
  }
  __syncthreads();
  __hip_bfloat16* op = xT + ((size_t)(b * 4096 + n0) * 512) + c0;
#pragma unroll
  for (int i = 0; i < 16; ++i) {
    int nl = ty + 4 * i;
    op[(size_t)nl * 512 + tx] = __float2bfloat16(tile[tx][nl]);
  }
}

// ---------------- NT GEMM: C(MxN) = A(MxK) . B(NxK)^T ----------------
template <int EPI>
__global__ __launch_bounds__(256) void gemm_nt_k(
    const __hip_bfloat16* __restrict__ A, long sA,
    const __hip_bfloat16* __restrict__ B, long sB,
    void* __restrict__ Cp, long sC,
    int lda, int ldb, int ldc, int K,
    const float* __restrict__ s, const float* __restrict__ t) {
  __shared__ short As[128][72];
  __shared__ short Bs[128][72];
  const int tid = threadIdx.x;
  const int w = tid >> 6, l = tid & 63, g = l >> 4, ln = l & 15;
  const int wr = w >> 1, wc = w & 1;
  const int rb = blockIdx.x * 128, cb = blockIdx.y * 128;
  const __hip_bfloat16* Ab = A + (size_t)blockIdx.z * sA;
  const __hip_bfloat16* Bb = B + (size_t)blockIdx.z * sB;

  f32x4 acc[4][4];
#pragma unroll
  for (int i = 0; i < 4; ++i)
#pragma unroll
    for (int j = 0; j < 4; ++j) acc[i][j] = (f32x4){0.f, 0.f, 0.f, 0.f};

  const int r0 = tid >> 3;
  const int c8 = (tid & 7) * 8;

  for (int k0 = 0; k0 < K; k0 += 64) {
#pragma unroll
    for (int i = 0; i < 4; ++i) {
      const int r = r0 + 32 * i;
      *(uint4*)&As[r][c8] = *(const uint4*)(Ab + (size_t)(rb + r) * lda + (k0 + c8));
      *(uint4*)&Bs[r][c8] = *(const uint4*)(Bb + (size_t)(cb + r) * ldb + (k0 + c8));
    }
    __syncthreads();
#pragma unroll
    for (int kk = 0; kk < 2; ++kk) {
      bf16x8 av[4], bv[4];
#pragma unroll
      for (int i = 0; i < 4; ++i) av[i] = *(const bf16x8*)&As[64 * wr + 16 * i + ln][32 * kk + 8 * g];
#pragma unroll
      for (int i = 0; i < 4; ++i) bv[i] = *(const bf16x8*)&Bs[64 * wc + 16 * i + ln][32 * kk + 8 * g];
#pragma unroll
      for (int mi = 0; mi < 4; ++mi)
#pragma unroll
        for (int ni = 0; ni < 4; ++ni)
          acc[mi][ni] = MFMA16(av[mi], bv[ni], acc[mi][ni]);
    }
    __syncthreads();
  }

  const int row0 = rb + 64 * wr + 4 * g;
  const int col0 = cb + 64 * wc + ln;

  if (EPI == 2) {
    float* C = (float*)Cp + (size_t)blockIdx.z * sC;
#pragma unroll
    for (int mi = 0; mi < 4; ++mi) {
#pragma unroll
      for (int r = 0; r < 4; ++r) {
        const int R = row0 + 16 * mi + r;
        const float sr = s[R], tr = t[R];
#pragma unroll
        for (int ni = 0; ni < 4; ++ni) {
          float v = fmaf(acc[mi][ni][r], sr, tr);
          C[(size_t)R * ldc + (col0 + 16 * ni)] = v > 0.f ? v : 0.f;
        }
      }
    }
  } else {
    __hip_bfloat16* C = (__hip_bfloat16*)Cp + (size_t)blockIdx.z * sC;
    float sc[4], tc[4];
    if (EPI == 1) {
#pragma unroll
      for (int ni = 0; ni < 4; ++ni) { sc[ni] = s[col0 + 16 * ni]; tc[ni] = t[col0 + 16 * ni]; }
    }
#pragma unroll
    for (int mi = 0; mi < 4; ++mi) {
#pragma unroll
      for (int ni = 0; ni < 4; ++ni) {
#pragma unroll
        for (int r = 0; r < 4; ++r) {
          float v = acc[mi][ni][r];
          if (EPI == 1) { v = fmaf(v, sc[ni], tc[ni]); v = v > 0.f ? v : 0.f; }
          C[(size_t)(row0 + 16 * mi + r) * ldc + (col0 + 16 * ni)] = __float2bfloat16(v);
        }
      }
    }
  }
}

// ---------------- flash attention v5: deep pipeline ----------------
// Q,K: (B,4096,256) bf16; V: (B,256,4096) bf16; O: (B,4096,256) bf16
// 512 blocks (2/CU): batch = bid&7 (XCD-pinned), 64 q-rows/block, 4 waves.
// K LDS double-buffered (2x32KB); V double-buffered in regs (issued 1 tile
// ahead); P single 8KB shared buffer. 2 barriers/iter, counted vmcnt only.
__global__ __launch_bounds__(256, 2) void flash_k(
    const __hip_bfloat16* __restrict__ Q,
    const __hip_bfloat16* __restrict__ Kt,
    const __hip_bfloat16* __restrict__ V,
    __hip_bfloat16* __restrict__ O) {
  __shared__ short Ks[2][64 * 256];  // 2 x 32 KB swizzled K tiles
  __shared__ short Ps[64 * 64];      // 8 KB swizzled block-shared P
  __shared__ float aLds[64];
  __shared__ float lLds[64];
  __shared__ int fLds[4];

  const int tid = threadIdx.x;
  const int w = tid >> 6, l = tid & 63, g = l >> 4, ln = l & 15;
  const int bid = blockIdx.x;
  const int batch = bid & 7;
  const int qb = (bid >> 3) << 6;
  const size_t bo = (size_t)batch * (4096 * 256);
  const float CE = 0.09016844005556021f;  // log2(e)/sqrt(256)

  // hoisted LDS addressing (XOR swizzle on byte bits 4-6)
  const int swz45 = (16 * g) ^ ((ln & 3) << 4);
  const int s6 = ((ln >> 2) & 1) << 6;
  const char* Ka0 = (const char*)Ks[0] + (ln * 512 + swz45 + s6);
  const char* Ka1 = Ka0 + (((ln >> 2) & 1) ? -64 : 64);
  const char* Kb0 = Ka0 + 32768;
  const char* Kb1 = Ka1 + 32768;
  const char* Pr0 = (const char*)Ps + (ln * 128 + swz45 + s6);
  const char* Pr1 = Pr0 + (((ln >> 2) & 1) ? -64 : 64);
  const int pwOff = (16 * w + ln) * 128 + 8 * (g & 1) + (((g >> 1) ^ (ln & 1)) << 4) +
                    (((ln >> 1) & 1) << 5) + s6;

  // Q fragments (B-operand): lane ln = q-row (16w+ln), k = 32kk+8g+j
  bf16x8 qf[8];
  {
    const __hip_bfloat16* qp = Q + bo + (size_t)(qb + 16 * w + ln) * 256 + 8 * g;
#pragma unroll
    for (int kk = 0; kk < 8; ++kk) qf[kk] = *(const bf16x8*)(qp + 32 * kk);
  }

  f32x4 acc[4][4];  // [qg][ci]: rows q=16qg+4g+r, cols cv=64w+16ci+ln
#pragma unroll
  for (int qg = 0; qg < 4; ++qg)
#pragma unroll
    for (int ci = 0; ci < 4; ++ci) acc[qg][ci] = (f32x4){0.f, 0.f, 0.f, 0.f};
  float m_run = -1e30f, l_run = 0.f;

  // staging pointers (hand-maintained, advance per tile)
  const int kRow = 16 * w + (l >> 5);
  const int kChunk = (l & 31) ^ (l >> 5);
  const short* kPtr[8];
#pragma unroll
  for (int j = 0; j < 8; ++j)
    kPtr[j] = (const short*)(Kt + bo) + (size_t)(kRow + 2 * j) * 256 + 8 * (kChunk ^ ((2 * j) & 7));
  const short* vPtr[4];
#pragma unroll
  for (int ci = 0; ci < 4; ++ci)
    vPtr[ci] = (const short*)(V + bo) + (size_t)(64 * w + 16 * ci + ln) * 4096 + 8 * g;

  bf16x8 vfrA[8], vfrB[8];

#define STAGEK(NB)                                                     \
  do {                                                                 \
    _Pragma("unroll") for (int j = 0; j < 8; ++j) {                    \
      gload16(kPtr[j], (short*)Ks[NB] + w * 4096 + j * 512);           \
      kPtr[j] += 16384; /* 64 rows x 256 shorts */                     \
    }                                                                  \
  } while (0)

#define ISSUEV(VARR)                                                   \
  do {                                                                 \
    _Pragma("unroll") for (int ci = 0; ci < 4; ++ci) {                 \
      asm volatile("global_load_dwordx4 %0, %2, off\n\t"               \
                   "global_load_dwordx4 %1, %2, off offset:64"         \
                   : "=&v"(VARR[2 * ci]), "=&v"(VARR[2 * ci + 1])      \
                   : "v"(vPtr[ci]));                                   \
      vPtr[ci] += 64; /* 64 shorts = 128 B per tile */                 \
    }                                                                  \
  } while (0)

  // prologue: K(0) -> Ks[0], V(0) -> vfrA
  STAGEK(0);
  __builtin_amdgcn_sched_barrier(0);
  ISSUEV(vfrA);
  __builtin_amdgcn_sched_barrier(0);

#define BODY(T, K0P, K1P, VCUR, VNXT, NB)                                      \
  do {                                                                         \
    /* wait K(T) landed (8 younger V(T) loads outstanding) */                  \
    asm volatile("s_waitcnt vmcnt(8)" ::: "memory");                           \
    __builtin_amdgcn_sched_barrier(0);                                         \
    /* QK^T: lane ln = q-row, keys 16mi+4g+r */                                \
    f32x4 sf[4];                                                               \
    _Pragma("unroll") for (int mi = 0; mi < 4; ++mi)                           \
        sf[mi] = (f32x4){0.f, 0.f, 0.f, 0.f};                                  \
    __builtin_amdgcn_s_setprio(1);                                             \
    _Pragma("unroll") for (int kk = 0; kk < 8; ++kk) {                         \
      const char* kp = ((kk & 1) ? K1P : K0P) + 128 * (kk >> 1);               \
      _Pragma("unroll") for (int mi = 0; mi < 4; ++mi) {                       \
        bf16x8 a = *(const bf16x8*)(kp + 8192 * mi);                           \
        sf[mi] = MFMA16(a, qf[kk], sf[mi]);                                    \
      }                                                                        \
    }                                                                          \
    __builtin_amdgcn_s_setprio(0);                                             \
    __builtin_amdgcn_sched_barrier(0);                                         \
    if ((T) < 63) {                                                            \
      STAGEK(NB); /* K(T+1), flies a full iter */                              \
      __builtin_amdgcn_sched_barrier(0);                                       \
      ISSUEV(VNXT); /* V(T+1), consumed at PV(T+1) */                          \
      __builtin_amdgcn_sched_barrier(0);                                       \
    }                                                                          \
    /* online softmax (per q-row = ln) */                                      \
    float sv[16];                                                              \
    _Pragma("unroll") for (int mi = 0; mi < 4; ++mi)                           \
        _Pragma("unroll") for (int r = 0; r < 4; ++r)                          \
        sv[4 * mi + r] = sf[mi][r];                                            \
    float a0 = fmaxf(fmaxf(sv[0], sv[1]), sv[2]);                              \
    float a1 = fmaxf(fmaxf(sv[3], sv[4]), sv[5]);                              \
    float a2 = fmaxf(fmaxf(sv[6], sv[7]), sv[8]);                              \
    float a3 = fmaxf(fmaxf(sv[9], sv[10]), sv[11]);                            \
    float a4 = fmaxf(fmaxf(sv[12], sv[13]), sv[14]);                           \
    float mmax = fmaxf(fmaxf(fmaxf(fmaxf(a0, a1), a2), fmaxf(a3, a4)), sv[15]);\
    mmax = fmaxf(mmax, __shfl_xor(mmax, 16));                                  \
    mmax = fmaxf(mmax, __shfl_xor(mmax, 32));                                  \
    float alpha = 1.0f;                                                        \
    int rs = 0;                                                                \
    if (!__all((mmax - m_run) * CE <= 8.0f)) {                                 \
      float m_new = fmaxf(m_run, mmax);                                        \
      alpha = exp2f((m_run - m_new) * CE);                                     \
      l_run *= alpha;                                                          \
      m_run = m_new;                                                           \
      rs = 1;                                                                  \
    }                                                                          \
    float p[16], psum = 0.f;                                                   \
    _Pragma("unroll") for (int j = 0; j < 16; ++j) {                           \
      p[j] = exp2f((sv[j] - m_run) * CE);                                      \
      psum += p[j];                                                            \
    }                                                                          \
    psum += __shfl_xor(psum, 16);                                              \
    psum += __shfl_xor(psum, 32);                                              \
    l_run += psum;                                                             \
    {                                                                          \
      uint2 pk0, pk1, pk2, pk3;                                                \
      pk0.x = (unsigned)f2bf(p[0]) | ((unsigned)f2bf(p[1]) << 16);             \
      pk0.y = (unsigned)f2bf(p[2]) | ((unsigned)f2bf(p[3]) << 16);             \
      pk1.x = (unsigned)f2bf(p[4]) | ((unsigned)f2bf(p[5]) << 16);             \
      pk1.y = (unsigned)f2bf(p[6]) | ((unsigned)f2bf(p[7]) << 16);             \
      pk2.x = (unsigned)f2bf(p[8]) | ((unsigned)f2bf(p[9]) << 16);             \
      pk2.y = (unsigned)f2bf(p[10]) | ((unsigned)f2bf(p[11]) << 16);           \
      pk3.x = (unsigned)f2bf(p[12]) | ((unsigned)f2bf(p[13]) << 16);           \
      pk3.y = (unsigned)f2bf(p[14]) | ((unsigned)f2bf(p[15]) << 16);           \
      char* Pb = (char*)Ps;                                                    \
      *(uint2*)(Pb + (pwOff ^ 0)) = pk0;                                       \
      *(uint2*)(Pb + (pwOff ^ 32)) = pk1;                                      \
      *(uint2*)(Pb + (pwOff ^ 64)) = pk2;                                      \
      *(uint2*)(Pb + (pwOff ^ 96)) = pk3;                                      \
    }                                                                          \
    if (g == 0) aLds[16 * w + ln] = alpha;                                     \
    if (l == 0) fLds[w] = rs;                                                  \
    /* barrier A: P/alpha visible to all waves */                              \
    asm volatile("s_waitcnt lgkmcnt(0)" ::: "memory");                         \
    __builtin_amdgcn_sched_barrier(0);                                         \
    __builtin_amdgcn_s_barrier();                                              \
    asm volatile("" ::: "memory");                                             \
    __builtin_amdgcn_sched_barrier(0);                                         \
    /* rescale acc if any wave triggered this tile */                          \
    {                                                                          \
      int4 fl = *(const int4*)fLds;                                            \
      if (fl.x | fl.y | fl.z | fl.w) {                                         \
        _Pragma("unroll") for (int qg = 0; qg < 4; ++qg) {                     \
          f32x4 av = *(const f32x4*)&aLds[16 * qg + 4 * g];                    \
          _Pragma("unroll") for (int ci = 0; ci < 4; ++ci) acc[qg][ci] *= av;  \
        }                                                                      \
      }                                                                        \
    }                                                                          \
    /* wait V(T): K(T+1)+V(T+1) (16) may stay in flight */                     \
    if ((T) < 63) {                                                            \
      asm volatile("s_waitcnt vmcnt(16)" ::: "memory");                        \
    } else {                                                                   \
      asm volatile("s_waitcnt vmcnt(0)" ::: "memory");                         \
    }                                                                          \
    __builtin_amdgcn_sched_barrier(0);                                         \
    /* PV: acc[qg][ci] += P(q,keys) . V^T(keys,cv) */                          \
    __builtin_amdgcn_s_setprio(1);                                             \
    _Pragma("unroll") for (int kk = 0; kk < 2; ++kk) {                         \
      _Pragma("unroll") for (int qg = 0; qg < 4; ++qg) {                       \
        bf16x8 pa = *(const bf16x8*)((kk ? Pr1 : Pr0) + 2048 * qg);            \
        _Pragma("unroll") for (int ci = 0; ci < 4; ++ci)                       \
            acc[qg][ci] = MFMA16(pa, VCUR[2 * ci + kk], acc[qg][ci]);          \
      }                                                                        \
    }                                                                          \
    __builtin_amdgcn_s_setprio(0);                                             \
    __builtin_amdgcn_sched_barrier(0);                                         \
    /* barrier B: P(T)/aLds reads done before T+1 writes them */               \
    __builtin_amdgcn_s_barrier();                                              \
    asm volatile("" ::: "memory");                                             \
    __builtin_amdgcn_sched_barrier(0);                                         \
  } while (0)

  for (int tp = 0; tp < 32; ++tp) {
    const int t0 = 2 * tp;
    BODY(t0, Ka0, Ka1, vfrA, vfrB, 1);
    BODY(t0 + 1, Kb0, Kb1, vfrB, vfrA, 0);
  }
#undef BODY
#undef STAGEK
#undef ISSUEV

  // epilogue: share row sums, normalize, store
  if (g == 0) lLds[16 * w + ln] = l_run;
  __syncthreads();

  __hip_bfloat16* Ob = O + bo;
#pragma unroll
  for (int qg = 0; qg < 4; ++qg) {
    f32x4 lv = *(const f32x4*)&lLds[16 * qg + 4 * g];
    f32x4 li;
#pragma unroll
    for (int r = 0; r < 4; ++r) li[r] = 1.0f / lv[r];
#pragma unroll
    for (int ci = 0; ci < 4; ++ci) {
#pragma unroll
      for (int r = 0; r < 4; ++r) {
        float val = acc[qg][ci][r] * li[r];
        Ob[(size_t)(qb + 16 * qg + 4 * g + r) * 256 + 64 * w + 16 * ci + ln] = __float2bfloat16(val);
      }
    }
  }
}

// ---------------- host launcher ----------------

extern "C" void kernel_launch(void* const* d_in, const int* in_sizes, int n_in,
                              void* d_out, int out_size, void* d_ws, size_t ws_size,
                              hipStream_t stream) {
  const float* x   = (const float*)d_in[0];
  const float* kW1 = (const float*)d_in[1];
  const float* kG1 = (const float*)d_in[2];
  const float* kB1 = (const float*)d_in[3];
  const float* kM1 = (const float*)d_in[4];
  const float* kV1 = (const float*)d_in[5];
  const float* kW2 = (const float*)d_in[6];
  const float* kG2 = (const float*)d_in[7];
  const float* kB2 = (const float*)d_in[8];
  const float* kM2 = (const float*)d_in[9];
  const float* kV2 = (const float*)d_in[10];
  const float* qW1 = (const float*)d_in[11];
  const float* qG1 = (const float*)d_in[12];
  const float* qB1 = (const float*)d_in[13];
  const float* qM1 = (const float*)d_in[14];
  const float* qV1 = (const float*)d_in[15];
  const float* qW2 = (const float*)d_in[16];
  const float* qG2 = (const float*)d_in[17];
  const float* qB2 = (const float*)d_in[18];
  const float* qM2 = (const float*)d_in[19];
  const float* qV2 = (const float*)d_in[20];
  const float* vW  = (const float*)d_in[21];
  const float* wW  = (const float*)d_in[22];
  const float* wG  = (const float*)d_in[23];
  const float* wB  = (const float*)d_in[24];
  const float* wM  = (const float*)d_in[25];
  const float* wV  = (const float*)d_in[26];

  char* ws = (char*)d_ws;
  __hip_bfloat16* bQW1 = (__hip_bfloat16*)(ws + 0);
  __hip_bfloat16* bKW1 = (__hip_bfloat16*)(ws + 262144);
  __hip_bfloat16* bQW2 = (__hip_bfloat16*)(ws + 524288);
  __hip_bfloat16* bKW2 = (__hip_bfloat16*)(ws + 655360);
  __hip_bfloat16* bVW  = (__hip_bfloat16*)(ws + 786432);
  __hip_bfloat16* bWW  = (__hip_bfloat16*)(ws + 1048576);
  float* bnBase = (float*)(ws + 1310720);
  float* sQ1 = bnBase + 0;
  float* tQ1 = bnBase + 256;
  float* sQ2 = bnBase + 512;
  float* tQ2 = bnBase + 768;
  float* sK1 = bnBase + 1024;
  float* tK1 = bnBase + 1280;
  float* sK2 = bnBase + 1536;
  float* tK2 = bnBase + 1792;
  float* sWo = bnBase + 2048;
  float* tWo = bnBase + 2560;
  __hip_bfloat16* xT   = (__hip_bfloat16*)(ws + 2097152);    // 32 MB
  __hip_bfloat16* bufA = (__hip_bfloat16*)(ws + 35651584);   // 16 MB (q1 / k1 / ctx)
  __hip_bfloat16* q2b  = (__hip_bfloat16*)(ws + 52428800);   // 16 MB
  __hip_bfloat16* k2b  = (__hip_bfloat16*)(ws + 69206016);   // 16 MB
  __hip_bfloat16* vB   = (__hip_bfloat16*)(ws + 85983232);   // 16 MB

  conv_w_k<<<2560, 256, 0, stream>>>(qW1, kW1, qW2, kW2, vW, wW, bQW1);
  bn_all_k<<<6, 256, 0, stream>>>(qG1, qB1, qM1, qV1, qG2, qB2, qM2, qV2,
                                  kG1, kB1, kM1, kV1, kG2, kB2, kM2, kV2,
                                  wG, wB, wM, wV, bnBase);

  transpose_k<<<dim3(64, 8, 8), dim3(64, 4), 0, stream>>>(x, xT);

  // q1 = CBR(xT . qW1^T)
  gemm_nt_k<1><<<dim3(32, 2, 8), 256, 0, stream>>>(xT, 2097152L, bQW1, 0L, bufA, 1048576L,
                                                   512, 512, 256, 512, sQ1, tQ1);
  // q2 = CBR(q1 . qW2^T)
  gemm_nt_k<1><<<dim3(32, 2, 8), 256, 0, stream>>>(bufA, 1048576L, bQW2, 0L, q2b, 1048576L,
                                                   256, 256, 256, 256, sQ2, tQ2);
  // k1
  gemm_nt_k<1><<<dim3(32, 2, 8), 256, 0, stream>>>(xT, 2097152L, bKW1, 0L, bufA, 1048576L,
                                                   512, 512, 256, 512, sK1, tK1);
  // k2
  gemm_nt_k<1><<<dim3(32, 2, 8), 256, 0, stream>>>(bufA, 1048576L, bKW2, 0L, k2b, 1048576L,
                                                   256, 256, 256, 256, sK2, tK2);
  // v = vW . x -> (256 x 4096 per batch)
  gemm_nt_k<0><<<dim3(2, 32, 8), 256, 0, stream>>>(bVW, 0L, xT, 2097152L, vB, 1048576L,
                                                   512, 512, 4096, 512, nullptr, nullptr);
  // flash attention: ctx -> bufA
  flash_k<<<512, 256, 0, stream>>>(q2b, k2b, vB, bufA);
  // out = CBR_row(wW . ctx^T) -> d_out (fp32)
  gemm_nt_k<2><<<dim3(4, 32, 8), 256, 0, stream>>>(bWW, 0L, bufA, 1048576L, d_out, 2097152L,
                                                   256, 256, 4096, 256, sWo, tWo);
}

// Round 7
// 305.000 us; speedup vs baseline: 1.2058x; 1.2058x over previous
//
#include <hip/hip_runtime.h>
#include <hip/hip_bf16.h>

typedef __attribute__((ext_vector_type(8))) short bf16x8;
typedef __attribute__((ext_vector_type(4))) float f32x4;

#define MFMA16(a, b, c) __builtin_amdgcn_mfma_f32_16x16x32_bf16(a, b, c, 0, 0, 0)

static __device__ __forceinline__ unsigned short f2bf(float f) {
  union { __hip_bfloat16 h; unsigned short u; } cv;
  cv.h = __float2bfloat16(f);
  return cv.u;
}

static __device__ __forceinline__ void gload16(const void* gptr, void* lptr) {
  __builtin_amdgcn_global_load_lds(
      (const __attribute__((address_space(1))) void*)gptr,
      (__attribute__((address_space(3))) void*)lptr, 16, 0, 0);
}

// ---------------- fused prep kernels ----------------

__global__ void conv_w_k(const float* __restrict__ qW1, const float* __restrict__ kW1,
                         const float* __restrict__ qW2, const float* __restrict__ kW2,
                         const float* __restrict__ vW, const float* __restrict__ wW,
                         __hip_bfloat16* __restrict__ dst) {
  int i = blockIdx.x * 256 + threadIdx.x;  // 0..655359
  const float* src; int off;
  if (i < 131072)      { src = qW1; off = i; }
  else if (i < 262144) { src = kW1; off = i - 131072; }
  else if (i < 327680) { src = qW2; off = i - 262144; }
  else if (i < 393216) { src = kW2; off = i - 327680; }
  else if (i < 524288) { src = vW;  off = i - 393216; }
  else                 { src = wW;  off = i - 524288; }
  dst[i] = __float2bfloat16(src[off]);
}

__global__ void bn_all_k(const float* __restrict__ qG1, const float* __restrict__ qB1, const float* __restrict__ qM1, const float* __restrict__ qV1,
                         const float* __restrict__ qG2, const float* __restrict__ qB2, const float* __restrict__ qM2, const float* __restrict__ qV2,
                         const float* __restrict__ kG1, const float* __restrict__ kB1, const float* __restrict__ kM1, const float* __restrict__ kV1,
                         const float* __restrict__ kG2, const float* __restrict__ kB2, const float* __restrict__ kM2, const float* __restrict__ kV2,
                         const float* __restrict__ wG, const float* __restrict__ wB, const float* __restrict__ wM, const float* __restrict__ wV,
                         float* __restrict__ base) {
  int bidx = blockIdx.x, tid = threadIdx.x;
  const float *g, *b, *m, *v; float *s, *t; int i;
  if (bidx == 0)      { g = qG1; b = qB1; m = qM1; v = qV1; s = base;        t = base + 256;  i = tid; }
  else if (bidx == 1) { g = qG2; b = qB2; m = qM2; v = qV2; s = base + 512;  t = base + 768;  i = tid; }
  else if (bidx == 2) { g = kG1; b = kB1; m = kM1; v = kV1; s = base + 1024; t = base + 1280; i = tid; }
  else if (bidx == 3) { g = kG2; b = kB2; m = kM2; v = kV2; s = base + 1536; t = base + 1792; i = tid; }
  else                { g = wG;  b = wB;  m = wM;  v = wV;  s = base + 2048; t = base + 2560; i = (bidx - 4) * 256 + tid; }
  float sv = g[i] * rsqrtf(v[i] + 1e-5f);
  s[i] = sv;
  t[i] = b[i] - m[i] * sv;
}

// x (B,512,4096) fp32 -> xT (B,4096,512) bf16
__global__ __launch_bounds__(256) void transpose_k(const float* __restrict__ x,
                                                   __hip_bfloat16* __restrict__ xT) {
  __shared__ float tile[64][65];
  const int n0 = blockIdx.x * 64, c0 = blockIdx.y * 64, b = blockIdx.z;
  const int tx = threadIdx.x, ty = threadIdx.y;
  const float* xp = x + ((size_t)(b * 512 + c0) * 4096) + n0;
#pragma unroll
  for (int i = 0; i < 16; ++i) {
    int c = ty + 4 * i;
    tile[c][tx] = xp[(size_t)c * 4096 + tx];
  }
  __syncthreads();
  __hip_bfloat16* op = xT + ((size_t)(b * 4096 + n0) * 512) + c0;
#pragma unroll
  for (int i = 0; i < 16; ++i) {
    int nl = ty + 4 * i;
    op[(size_t)nl * 512 + tx] = __float2bfloat16(tile[tx][nl]);
  }
}

// ---------------- NT GEMM: C(MxN) = A(MxK) . B(NxK)^T ----------------
template <int EPI>
__global__ __launch_bounds__(256) void gemm_nt_k(
    const __hip_bfloat16* __restrict__ A, long sA,
    const __hip_bfloat16* __restrict__ B, long sB,
    void* __restrict__ Cp, long sC,
    int lda, int ldb, int ldc, int K,
    const float* __restrict__ s, const float* __restrict__ t) {
  __shared__ short As[128][72];
  __shared__ short Bs[128][72];
  const int tid = threadIdx.x;
  const int w = tid >> 6, l = tid & 63, g = l >> 4, ln = l & 15;
  const int wr = w >> 1, wc = w & 1;
  const int rb = blockIdx.x * 128, cb = blockIdx.y * 128;
  const __hip_bfloat16* Ab = A + (size_t)blockIdx.z * sA;
  const __hip_bfloat16* Bb = B + (size_t)blockIdx.z * sB;

  f32x4 acc[4][4];
#pragma unroll
  for (int i = 0; i < 4; ++i)
#pragma unroll
    for (int j = 0; j < 4; ++j) acc[i][j] = (f32x4){0.f, 0.f, 0.f, 0.f};

  const int r0 = tid >> 3;
  const int c8 = (tid & 7) * 8;

  for (int k0 = 0; k0 < K; k0 += 64) {
#pragma unroll
    for (int i = 0; i < 4; ++i) {
      const int r = r0 + 32 * i;
      *(uint4*)&As[r][c8] = *(const uint4*)(Ab + (size_t)(rb + r) * lda + (k0 + c8));
      *(uint4*)&Bs[r][c8] = *(const uint4*)(Bb + (size_t)(cb + r) * ldb + (k0 + c8));
    }
    __syncthreads();
#pragma unroll
    for (int kk = 0; kk < 2; ++kk) {
      bf16x8 av[4], bv[4];
#pragma unroll
      for (int i = 0; i < 4; ++i) av[i] = *(const bf16x8*)&As[64 * wr + 16 * i + ln][32 * kk + 8 * g];
#pragma unroll
      for (int i = 0; i < 4; ++i) bv[i] = *(const bf16x8*)&Bs[64 * wc + 16 * i + ln][32 * kk + 8 * g];
#pragma unroll
      for (int mi = 0; mi < 4; ++mi)
#pragma unroll
        for (int ni = 0; ni < 4; ++ni)
          acc[mi][ni] = MFMA16(av[mi], bv[ni], acc[mi][ni]);
    }
    __syncthreads();
  }

  const int row0 = rb + 64 * wr + 4 * g;
  const int col0 = cb + 64 * wc + ln;

  if (EPI == 2) {
    float* C = (float*)Cp + (size_t)blockIdx.z * sC;
#pragma unroll
    for (int mi = 0; mi < 4; ++mi) {
#pragma unroll
      for (int r = 0; r < 4; ++r) {
        const int R = row0 + 16 * mi + r;
        const float sr = s[R], tr = t[R];
#pragma unroll
        for (int ni = 0; ni < 4; ++ni) {
          float v = fmaf(acc[mi][ni][r], sr, tr);
          C[(size_t)R * ldc + (col0 + 16 * ni)] = v > 0.f ? v : 0.f;
        }
      }
    }
  } else {
    __hip_bfloat16* C = (__hip_bfloat16*)Cp + (size_t)blockIdx.z * sC;
    float sc[4], tc[4];
    if (EPI == 1) {
#pragma unroll
      for (int ni = 0; ni < 4; ++ni) { sc[ni] = s[col0 + 16 * ni]; tc[ni] = t[col0 + 16 * ni]; }
    }
#pragma unroll
    for (int mi = 0; mi < 4; ++mi) {
#pragma unroll
      for (int ni = 0; ni < 4; ++ni) {
#pragma unroll
        for (int r = 0; r < 4; ++r) {
          float v = acc[mi][ni][r];
          if (EPI == 1) { v = fmaf(v, sc[ni], tc[ni]); v = v > 0.f ? v : 0.f; }
          C[(size_t)(row0 + 16 * mi + r) * ldc + (col0 + 16 * ni)] = __float2bfloat16(v);
        }
      }
    }
  }
}

// ---------------- flash attention v7: 1-tile software pipeline ----------------
// Q,K: (B,4096,256) bf16; V: (B,256,4096) bf16; O: (B,4096,256) bf16
// 512 blocks (2/CU): batch = bid&7 (XCD-pinned), 64 q-rows/block, 4 waves.
// Per iter t: QK(t) + PV(t-1) back-to-back (64 MFMA), softmax(t) after
// barrier B. K LDS double-buffered; V single register buffer (reissued after
// consumption); P single 8KB shared buffer. 2 barriers/iter, counted vmcnt.
__global__ __launch_bounds__(256, 2) void flash_k(
    const __hip_bfloat16* __restrict__ Q,
    const __hip_bfloat16* __restrict__ Kt,
    const __hip_bfloat16* __restrict__ V,
    __hip_bfloat16* __restrict__ O) {
  __shared__ short Ks[2][64 * 256];  // 2 x 32 KB swizzled K tiles
  __shared__ short Ps[64 * 64];      // 8 KB swizzled block-shared P
  __shared__ float aLds[64];
  __shared__ float lLds[64];
  __shared__ int fLds[4];

  const int tid = threadIdx.x;
  const int w = tid >> 6, l = tid & 63, g = l >> 4, ln = l & 15;
  const int bid = blockIdx.x;
  const int batch = bid & 7;
  const int qb = (bid >> 3) << 6;
  const size_t bo = (size_t)batch * (4096 * 256);
  const float CE = 0.09016844005556021f;  // log2(e)/sqrt(256)

  // hoisted LDS addressing (XOR swizzle on byte bits 4-6)
  const int swz45 = (16 * g) ^ ((ln & 3) << 4);
  const int s6 = ((ln >> 2) & 1) << 6;
  const char* KA0 = (const char*)Ks[0] + (ln * 512 + swz45 + s6);
  const char* KA1 = KA0 + (((ln >> 2) & 1) ? -64 : 64);
  const char* KB0 = KA0 + 32768;
  const char* KB1 = KA1 + 32768;
  const char* Pr0 = (const char*)Ps + (ln * 128 + swz45 + s6);
  const char* Pr1 = Pr0 + (((ln >> 2) & 1) ? -64 : 64);
  const int pwOff = (16 * w + ln) * 128 + 8 * (g & 1) + (((g >> 1) ^ (ln & 1)) << 4) +
                    (((ln >> 1) & 1) << 5) + s6;

  // Q fragments (B-operand): lane ln = q-row (16w+ln), k = 32kk+8g+j
  bf16x8 qf[8];
  {
    const __hip_bfloat16* qp = Q + bo + (size_t)(qb + 16 * w + ln) * 256 + 8 * g;
#pragma unroll
    for (int kk = 0; kk < 8; ++kk) qf[kk] = *(const bf16x8*)(qp + 32 * kk);
  }

  f32x4 acc[4][4];  // [qg][ci]: rows q=16qg+4g+r, cols cv=64w+16ci+ln
#pragma unroll
  for (int qg = 0; qg < 4; ++qg)
#pragma unroll
    for (int ci = 0; ci < 4; ++ci) acc[qg][ci] = (f32x4){0.f, 0.f, 0.f, 0.f};
  float m_run = -1e30f, l_run = 0.f;
  f32x4 sf[4];
  bf16x8 vfr[8];

  const int kRow = 16 * w + (l >> 5);
  const int kChunk = (l & 31) ^ (l >> 5);
  const short* Kb = (const short*)(Kt + bo);
  const short* Vp = (const short*)(V + bo) + (size_t)(64 * w + ln) * 4096 + 8 * g;

#define SB __builtin_amdgcn_sched_barrier(0)

#define STAGEK(NB, M0)                                                         \
  do {                                                                         \
    _Pragma("unroll") for (int j = 0; j < 8; ++j) {                            \
      const short* gp =                                                        \
          Kb + (size_t)((M0) + kRow + 2 * j) * 256 + 8 * (kChunk ^ ((2 * j) & 7)); \
      gload16(gp, (short*)Ks[NB] + w * 4096 + j * 512);                        \
    }                                                                          \
  } while (0)

#define ISSUEV(M0)                                                             \
  do {                                                                         \
    _Pragma("unroll") for (int ci = 0; ci < 4; ++ci)                           \
        _Pragma("unroll") for (int kk = 0; kk < 2; ++kk) {                     \
      const short* gp = Vp + (size_t)ci * (16 * 4096) + ((M0) + 32 * kk);      \
      asm volatile("global_load_dwordx4 %0, %1, off"                           \
                   : "=v"(vfr[2 * ci + kk]) : "v"(gp));                        \
    }                                                                          \
  } while (0)

#define QKP(K0P, K1P)                                                          \
  do {                                                                         \
    _Pragma("unroll") for (int mi = 0; mi < 4; ++mi)                           \
        sf[mi] = (f32x4){0.f, 0.f, 0.f, 0.f};                                  \
    __builtin_amdgcn_s_setprio(1);                                             \
    _Pragma("unroll") for (int kk = 0; kk < 8; ++kk) {                         \
      const char* kp = ((kk & 1) ? (K1P) : (K0P)) + 128 * (kk >> 1);           \
      _Pragma("unroll") for (int mi = 0; mi < 4; ++mi) {                       \
        bf16x8 a = *(const bf16x8*)(kp + 8192 * mi);                           \
        sf[mi] = MFMA16(a, qf[kk], sf[mi]);                                    \
      }                                                                        \
    }                                                                          \
    __builtin_amdgcn_s_setprio(0);                                             \
  } while (0)

#define RESCALE                                                                \
  do {                                                                         \
    int4 fl = *(const int4*)fLds;                                              \
    if (fl.x | fl.y | fl.z | fl.w) {                                           \
      _Pragma("unroll") for (int qg = 0; qg < 4; ++qg) {                       \
        f32x4 av = *(const f32x4*)&aLds[16 * qg + 4 * g];                      \
        _Pragma("unroll") for (int ci = 0; ci < 4; ++ci) acc[qg][ci] *= av;    \
      }                                                                        \
    }                                                                          \
  } while (0)

#define PVP                                                                    \
  do {                                                                         \
    __builtin_amdgcn_s_setprio(1);                                             \
    _Pragma("unroll") for (int kk = 0; kk < 2; ++kk) {                         \
      _Pragma("unroll") for (int qg = 0; qg < 4; ++qg) {                       \
        bf16x8 pa = *(const bf16x8*)((kk ? Pr1 : Pr0) + 2048 * qg);            \
        _Pragma("unroll") for (int ci = 0; ci < 4; ++ci)                       \
            acc[qg][ci] = MFMA16(pa, vfr[2 * ci + kk], acc[qg][ci]);           \
      }                                                                        \
    }                                                                          \
    __builtin_amdgcn_s_setprio(0);                                             \
  } while (0)

#define SOFTMAX                                                                \
  do {                                                                         \
    float sv[16];                                                              \
    _Pragma("unroll") for (int mi = 0; mi < 4; ++mi)                           \
        _Pragma("unroll") for (int r = 0; r < 4; ++r)                          \
        sv[4 * mi + r] = sf[mi][r];                                            \
    float a0 = fmaxf(fmaxf(sv[0], sv[1]), sv[2]);                              \
    float a1 = fmaxf(fmaxf(sv[3], sv[4]), sv[5]);                              \
    float a2 = fmaxf(fmaxf(sv[6], sv[7]), sv[8]);                              \
    float a3 = fmaxf(fmaxf(sv[9], sv[10]), sv[11]);                            \
    float a4 = fmaxf(fmaxf(sv[12], sv[13]), sv[14]);                           \
    float mmax = fmaxf(fmaxf(fmaxf(fmaxf(a0, a1), a2), fmaxf(a3, a4)), sv[15]);\
    mmax = fmaxf(mmax, __shfl_xor(mmax, 16));                                  \
    mmax = fmaxf(mmax, __shfl_xor(mmax, 32));                                  \
    float alpha = 1.0f;                                                        \
    int rs = 0;                                                                \
    if (!__all((mmax - m_run) * CE <= 8.0f)) {                                 \
      float m_new = fmaxf(m_run, mmax);                                        \
      alpha = exp2f((m_run - m_new) * CE);                                     \
      l_run *= alpha;                                                          \
      m_run = m_new;                                                           \
      rs = 1;                                                                  \
    }                                                                          \
    float p[16], psum = 0.f;                                                   \
    _Pragma("unroll") for (int j = 0; j < 16; ++j) {                           \
      p[j] = exp2f((sv[j] - m_run) * CE);                                      \
      psum += p[j];                                                            \
    }                                                                          \
    psum += __shfl_xor(psum, 16);                                              \
    psum += __shfl_xor(psum, 32);                                              \
    l_run += psum;                                                             \
    {                                                                          \
      uint2 pk0, pk1, pk2, pk3;                                                \
      pk0.x = (unsigned)f2bf(p[0]) | ((unsigned)f2bf(p[1]) << 16);             \
      pk0.y = (unsigned)f2bf(p[2]) | ((unsigned)f2bf(p[3]) << 16);             \
      pk1.x = (unsigned)f2bf(p[4]) | ((unsigned)f2bf(p[5]) << 16);             \
      pk1.y = (unsigned)f2bf(p[6]) | ((unsigned)f2bf(p[7]) << 16);             \
      pk2.x = (unsigned)f2bf(p[8]) | ((unsigned)f2bf(p[9]) << 16);             \
      pk2.y = (unsigned)f2bf(p[10]) | ((unsigned)f2bf(p[11]) << 16);           \
      pk3.x = (unsigned)f2bf(p[12]) | ((unsigned)f2bf(p[13]) << 16);           \
      pk3.y = (unsigned)f2bf(p[14]) | ((unsigned)f2bf(p[15]) << 16);           \
      char* Pb = (char*)Ps;                                                    \
      *(uint2*)(Pb + (pwOff ^ 0)) = pk0;                                       \
      *(uint2*)(Pb + (pwOff ^ 32)) = pk1;                                      \
      *(uint2*)(Pb + (pwOff ^ 64)) = pk2;                                      \
      *(uint2*)(Pb + (pwOff ^ 96)) = pk3;                                      \
    }                                                                          \
    if (g == 0) aLds[16 * w + ln] = alpha;                                     \
    if (l == 0) fLds[w] = rs;                                                  \
  } while (0)

  // body for t>=1: QK(t), stage K(t+1), rescale(alpha(t-1)), PV(t-1),
  // issue V(t), barrier B, softmax(t), barrier A.
#define BODY(K0P, K1P, NB, T, DOSTAGE)                                         \
  do {                                                                         \
    QKP(K0P, K1P);                                                             \
    SB;                                                                        \
    if (DOSTAGE) STAGEK(NB, ((T) + 1) << 6);                                   \
    SB;                                                                        \
    RESCALE;                                                                   \
    if (DOSTAGE) { asm volatile("s_waitcnt vmcnt(8)" ::: "memory"); }          \
    else         { asm volatile("s_waitcnt vmcnt(0)" ::: "memory"); }          \
    SB;                                                                        \
    PVP;                                                                       \
    SB;                                                                        \
    ISSUEV((T) << 6);                                                          \
    SB;                                                                        \
    asm volatile("s_waitcnt lgkmcnt(0)" ::: "memory");                         \
    SB;                                                                        \
    __builtin_amdgcn_s_barrier(); /* B: P/aLds readers done */                 \
    asm volatile("" ::: "memory");                                             \
    SB;                                                                        \
    SOFTMAX;                                                                   \
    asm volatile("s_waitcnt vmcnt(8) lgkmcnt(0)" ::: "memory");                \
    SB;                                                                        \
    __builtin_amdgcn_s_barrier(); /* A: K(t+1) landed, P(t) visible */         \
    asm volatile("" ::: "memory");                                             \
    SB;                                                                        \
  } while (0)

  // prologue (t=0): no PV
  STAGEK(0, 0);
  SB;
  asm volatile("s_waitcnt vmcnt(0)" ::: "memory");
  SB;
  __builtin_amdgcn_s_barrier();
  asm volatile("" ::: "memory");
  SB;
  QKP(KA0, KA1);
  SB;
  STAGEK(1, 64);
  SB;
  ISSUEV(0);
  SB;
  SOFTMAX;
  asm volatile("s_waitcnt vmcnt(8) lgkmcnt(0)" ::: "memory");
  SB;
  __builtin_amdgcn_s_barrier();  // A(0)
  asm volatile("" ::: "memory");
  SB;

  // t = 1..62 in parity pairs
  for (int m = 0; m < 31; ++m) {
    BODY(KB0, KB1, 0, 2 * m + 1, 1);
    BODY(KA0, KA1, 1, 2 * m + 2, 1);
  }
  // t = 63 (odd parity, no stage)
  BODY(KB0, KB1, 0, 63, 0);
  // final PV(63)
  RESCALE;
  asm volatile("s_waitcnt vmcnt(0)" ::: "memory");
  SB;
  PVP;

#undef BODY
#undef SOFTMAX
#undef PVP
#undef RESCALE
#undef QKP
#undef ISSUEV
#undef STAGEK
#undef SB

  // epilogue: share row sums, normalize, store
  if (g == 0) lLds[16 * w + ln] = l_run;
  __syncthreads();

  __hip_bfloat16* Ob = O + bo;
#pragma unroll
  for (int qg = 0; qg < 4; ++qg) {
    f32x4 lv = *(const f32x4*)&lLds[16 * qg + 4 * g];
    f32x4 li;
#pragma unroll
    for (int r = 0; r < 4; ++r) li[r] = 1.0f / lv[r];
#pragma unroll
    for (int ci = 0; ci < 4; ++ci) {
#pragma unroll
      for (int r = 0; r < 4; ++r) {
        float val = acc[qg][ci][r] * li[r];
        Ob[(size_t)(qb + 16 * qg + 4 * g + r) * 256 + 64 * w + 16 * ci + ln] = __float2bfloat16(val);
      }
    }
  }
}

// ---------------- host launcher ----------------

extern "C" void kernel_launch(void* const* d_in, const int* in_sizes, int n_in,
                              void* d_out, int out_size, void* d_ws, size_t ws_size,
                              hipStream_t stream) {
  const float* x   = (const float*)d_in[0];
  const float* kW1 = (const float*)d_in[1];
  const float* kG1 = (const float*)d_in[2];
  const float* kB1 = (const float*)d_in[3];
  const float* kM1 = (const float*)d_in[4];
  const float* kV1 = (const float*)d_in[5];
  const float* kW2 = (const float*)d_in[6];
  const float* kG2 = (const float*)d_in[7];
  const float* kB2 = (const float*)d_in[8];
  const float* kM2 = (const float*)d_in[9];
  const float* kV2 = (const float*)d_in[10];
  const float* qW1 = (const float*)d_in[11];
  const float* qG1 = (const float*)d_in[12];
  const float* qB1 = (const float*)d_in[13];
  const float* qM1 = (const float*)d_in[14];
  const float* qV1 = (const float*)d_in[15];
  const float* qW2 = (const float*)d_in[16];
  const float* qG2 = (const float*)d_in[17];
  const float* qB2 = (const float*)d_in[18];
  const float* qM2 = (const float*)d_in[19];
  const float* qV2 = (const float*)d_in[20];
  const float* vW  = (const float*)d_in[21];
  const float* wW  = (const float*)d_in[22];
  const float* wG  = (const float*)d_in[23];
  const float* wB  = (const float*)d_in[24];
  const float* wM  = (const float*)d_in[25];
  const float* wV  = (const float*)d_in[26];

  char* ws = (char*)d_ws;
  __hip_bfloat16* bQW1 = (__hip_bfloat16*)(ws + 0);
  __hip_bfloat16* bKW1 = (__hip_bfloat16*)(ws + 262144);
  __hip_bfloat16* bQW2 = (__hip_bfloat16*)(ws + 524288);
  __hip_bfloat16* bKW2 = (__hip_bfloat16*)(ws + 655360);
  __hip_bfloat16* bVW  = (__hip_bfloat16*)(ws + 786432);
  __hip_bfloat16* bWW  = (__hip_bfloat16*)(ws + 1048576);
  float* bnBase = (float*)(ws + 1310720);
  float* sQ1 = bnBase + 0;
  float* tQ1 = bnBase + 256;
  float* sQ2 = bnBase + 512;
  float* tQ2 = bnBase + 768;
  float* sK1 = bnBase + 1024;
  float* tK1 = bnBase + 1280;
  float* sK2 = bnBase + 1536;
  float* tK2 = bnBase + 1792;
  float* sWo = bnBase + 2048;
  float* tWo = bnBase + 2560;
  __hip_bfloat16* xT   = (__hip_bfloat16*)(ws + 2097152);    // 32 MB
  __hip_bfloat16* bufA = (__hip_bfloat16*)(ws + 35651584);   // 16 MB (q1 / k1 / ctx)
  __hip_bfloat16* q2b  = (__hip_bfloat16*)(ws + 52428800);   // 16 MB
  __hip_bfloat16* k2b  = (__hip_bfloat16*)(ws + 69206016);   // 16 MB
  __hip_bfloat16* vB   = (__hip_bfloat16*)(ws + 85983232);   // 16 MB

  conv_w_k<<<2560, 256, 0, stream>>>(qW1, kW1, qW2, kW2, vW, wW, bQW1);
  bn_all_k<<<6, 256, 0, stream>>>(qG1, qB1, qM1, qV1, qG2, qB2, qM2, qV2,
                                  kG1, kB1, kM1, kV1, kG2, kB2, kM2, kV2,
                                  wG, wB, wM, wV, bnBase);

  transpose_k<<<dim3(64, 8, 8), dim3(64, 4), 0, stream>>>(x, xT);

  // q1 = CBR(xT . qW1^T)
  gemm_nt_k<1><<<dim3(32, 2, 8), 256, 0, stream>>>(xT, 2097152L, bQW1, 0L, bufA, 1048576L,
                                                   512, 512, 256, 512, sQ1, tQ1);
  // q2 = CBR(q1 . qW2^T)
  gemm_nt_k<1><<<dim3(32, 2, 8), 256, 0, stream>>>(bufA, 1048576L, bQW2, 0L, q2b, 1048576L,
                                                   256, 256, 256, 256, sQ2, tQ2);
  // k1
  gemm_nt_k<1><<<dim3(32, 2, 8), 256, 0, stream>>>(xT, 2097152L, bKW1, 0L, bufA, 1048576L,
                                                   512, 512, 256, 512, sK1, tK1);
  // k2
  gemm_nt_k<1><<<dim3(32, 2, 8), 256, 0, stream>>>(bufA, 1048576L, bKW2, 0L, k2b, 1048576L,
                                                   256, 256, 256, 256, sK2, tK2);
  // v = vW . x -> (256 x 4096 per batch)
  gemm_nt_k<0><<<dim3(2, 32, 8), 256, 0, stream>>>(bVW, 0L, xT, 2097152L, vB, 1048576L,
                                                   512, 512, 4096, 512, nullptr, nullptr);
  // flash attention: ctx -> bufA
  flash_k<<<512, 256, 0, stream>>>(q2b, k2b, vB, bufA);
  // out = CBR_row(wW . ctx^T) -> d_out (fp32)
  gemm_nt_k<2><<<dim3(4, 32, 8), 256, 0, stream>>>(bWW, 0L, bufA, 1048576L, d_out, 2097152L,
                                                   256, 256, 4096, 256, sWo, tWo);
}

// Round 10
// 303.856 us; speedup vs baseline: 1.2103x; 1.0038x over previous
//
#include <hip/hip_runtime.h>
#include <hip/hip_bf16.h>

typedef __attribute__((ext_vector_type(8))) short bf16x8;
typedef __attribute__((ext_vector_type(4))) float f32x4;

#define MFMA16(a, b, c) __builtin_amdgcn_mfma_f32_16x16x32_bf16(a, b, c, 0, 0, 0)

static __device__ __forceinline__ unsigned short f2bf(float f) {
  union { __hip_bfloat16 h; unsigned short u; } cv;
  cv.h = __float2bfloat16(f);
  return cv.u;
}

static __device__ __forceinline__ float bf2f(short s) {
  union { float f; unsigned u; } cv;
  cv.u = ((unsigned)(unsigned short)s) << 16;
  return cv.f;
}

static __device__ __forceinline__ void gload16(const void* gptr, void* lptr) {
  __builtin_amdgcn_global_load_lds(
      (const __attribute__((address_space(1))) void*)gptr,
      (__attribute__((address_space(3))) void*)lptr, 16, 0, 0);
}

// ---------------- fused prep kernels ----------------

__global__ void conv_w_k(const float* __restrict__ qW1, const float* __restrict__ kW1,
                         const float* __restrict__ qW2, const float* __restrict__ kW2,
                         const float* __restrict__ vW, const float* __restrict__ wW,
                         __hip_bfloat16* __restrict__ dst) {
  int i = blockIdx.x * 256 + threadIdx.x;  // 0..655359
  const float* src; int off;
  if (i < 131072)      { src = qW1; off = i; }
  else if (i < 262144) { src = kW1; off = i - 131072; }
  else if (i < 327680) { src = qW2; off = i - 262144; }
  else if (i < 393216) { src = kW2; off = i - 327680; }
  else if (i < 524288) { src = vW;  off = i - 393216; }
  else                 { src = wW;  off = i - 524288; }
  dst[i] = __float2bfloat16(src[off]);
}

__global__ void bn_all_k(const float* __restrict__ qG1, const float* __restrict__ qB1, const float* __restrict__ qM1, const float* __restrict__ qV1,
                         const float* __restrict__ qG2, const float* __restrict__ qB2, const float* __restrict__ qM2, const float* __restrict__ qV2,
                         const float* __restrict__ kG1, const float* __restrict__ kB1, const float* __restrict__ kM1, const float* __restrict__ kV1,
                         const float* __restrict__ kG2, const float* __restrict__ kB2, const float* __restrict__ kM2, const float* __restrict__ kV2,
                         const float* __restrict__ wG, const float* __restrict__ wB, const float* __restrict__ wM, const float* __restrict__ wV,
                         float* __restrict__ base) {
  int bidx = blockIdx.x, tid = threadIdx.x;
  const float *g, *b, *m, *v; float *s, *t; int i;
  if (bidx == 0)      { g = qG1; b = qB1; m = qM1; v = qV1; s = base;        t = base + 256;  i = tid; }
  else if (bidx == 1) { g = qG2; b = qB2; m = qM2; v = qV2; s = base + 512;  t = base + 768;  i = tid; }
  else if (bidx == 2) { g = kG1; b = kB1; m = kM1; v = kV1; s = base + 1024; t = base + 1280; i = tid; }
  else if (bidx == 3) { g = kG2; b = kB2; m = kM2; v = kV2; s = base + 1536; t = base + 1792; i = tid; }
  else                { g = wG;  b = wB;  m = wM;  v = wV;  s = base + 2048; t = base + 2560; i = (bidx - 4) * 256 + tid; }
  float sv = g[i] * rsqrtf(v[i] + 1e-5f);
  s[i] = sv;
  t[i] = b[i] - m[i] * sv;
}

// x (B,512,4096) fp32 -> xT (B,4096,512) bf16
__global__ __launch_bounds__(256) void transpose_k(const float* __restrict__ x,
                                                   __hip_bfloat16* __restrict__ xT) {
  __shared__ float tile[64][65];
  const int n0 = blockIdx.x * 64, c0 = blockIdx.y * 64, b = blockIdx.z;
  const int tx = threadIdx.x, ty = threadIdx.y;
  const float* xp = x + ((size_t)(b * 512 + c0) * 4096) + n0;
#pragma unroll
  for (int i = 0; i < 16; ++i) {
    int c = ty + 4 * i;
    tile[c][tx] = xp[(size_t)c * 4096 + tx];
  }
  __syncthreads();
  __hip_bfloat16* op = xT + ((size_t)(b * 4096 + n0) * 512) + c0;
#pragma unroll
  for (int i = 0; i < 16; ++i) {
    int nl = ty + 4 * i;
    op[(size_t)nl * 512 + tx] = __float2bfloat16(tile[tx][nl]);
  }
}

// ---------------- NT GEMM: C(MxN) = A(MxK) . B(NxK)^T ----------------
template <int EPI>
__global__ __launch_bounds__(256) void gemm_nt_k(
    const __hip_bfloat16* __restrict__ A, long sA,
    const __hip_bfloat16* __restrict__ B, long sB,
    void* __restrict__ Cp, long sC,
    int lda, int ldb, int ldc, int K,
    const float* __restrict__ s, const float* __restrict__ t) {
  __shared__ short As[128][72];
  __shared__ short Bs[128][72];
  const int tid = threadIdx.x;
  const int w = tid >> 6, l = tid & 63, g = l >> 4, ln = l & 15;
  const int wr = w >> 1, wc = w & 1;
  const int rb = blockIdx.x * 128, cb = blockIdx.y * 128;
  const __hip_bfloat16* Ab = A + (size_t)blockIdx.z * sA;
  const __hip_bfloat16* Bb = B + (size_t)blockIdx.z * sB;

  f32x4 acc[4][4];
#pragma unroll
  for (int i = 0; i < 4; ++i)
#pragma unroll
    for (int j = 0; j < 4; ++j) acc[i][j] = (f32x4){0.f, 0.f, 0.f, 0.f};

  const int r0 = tid >> 3;
  const int c8 = (tid & 7) * 8;

  for (int k0 = 0; k0 < K; k0 += 64) {
#pragma unroll
    for (int i = 0; i < 4; ++i) {
      const int r = r0 + 32 * i;
      *(uint4*)&As[r][c8] = *(const uint4*)(Ab + (size_t)(rb + r) * lda + (k0 + c8));
      *(uint4*)&Bs[r][c8] = *(const uint4*)(Bb + (size_t)(cb + r) * ldb + (k0 + c8));
    }
    __syncthreads();
#pragma unroll
    for (int kk = 0; kk < 2; ++kk) {
      bf16x8 av[4], bv[4];
#pragma unroll
      for (int i = 0; i < 4; ++i) av[i] = *(const bf16x8*)&As[64 * wr + 16 * i + ln][32 * kk + 8 * g];
#pragma unroll
      for (int i = 0; i < 4; ++i) bv[i] = *(const bf16x8*)&Bs[64 * wc + 16 * i + ln][32 * kk + 8 * g];
#pragma unroll
      for (int mi = 0; mi < 4; ++mi)
#pragma unroll
        for (int ni = 0; ni < 4; ++ni)
          acc[mi][ni] = MFMA16(av[mi], bv[ni], acc[mi][ni]);
    }
    __syncthreads();
  }

  const int row0 = rb + 64 * wr + 4 * g;
  const int col0 = cb + 64 * wc + ln;

  if (EPI == 2) {
    float* C = (float*)Cp + (size_t)blockIdx.z * sC;
#pragma unroll
    for (int mi = 0; mi < 4; ++mi) {
#pragma unroll
      for (int r = 0; r < 4; ++r) {
        const int R = row0 + 16 * mi + r;
        const float sr = s[R], tr = t[R];
#pragma unroll
        for (int ni = 0; ni < 4; ++ni) {
          float v = fmaf(acc[mi][ni][r], sr, tr);
          C[(size_t)R * ldc + (col0 + 16 * ni)] = v > 0.f ? v : 0.f;
        }
      }
    }
  } else {
    __hip_bfloat16* C = (__hip_bfloat16*)Cp + (size_t)blockIdx.z * sC;
    float sc[4], tc[4];
    if (EPI == 1) {
#pragma unroll
      for (int ni = 0; ni < 4; ++ni) { sc[ni] = s[col0 + 16 * ni]; tc[ni] = t[col0 + 16 * ni]; }
    }
#pragma unroll
    for (int mi = 0; mi < 4; ++mi) {
#pragma unroll
      for (int ni = 0; ni < 4; ++ni) {
#pragma unroll
        for (int r = 0; r < 4; ++r) {
          float v = acc[mi][ni][r];
          if (EPI == 1) { v = fmaf(v, sc[ni], tc[ni]); v = v > 0.f ? v : 0.f; }
          C[(size_t)(row0 + 16 * mi + r) * ldc + (col0 + 16 * ni)] = __float2bfloat16(v);
        }
      }
    }
  }
}

// ---------------- flash attention v10: split-K + fixed-mhat ----------------
// 1024 blocks: batch=bid&7 (XCD), half=(bid>>3)&1, qb=(bid>>4)*64. 4 waves.
// QK q-split (K from 32KB LDS); PV cv-split (V global->regs); P via 8KB LDS.
// LDS = 40960 B -> 4 blocks/CU when VGPR <= 128.
// __launch_bounds__(256,2): do NOT force VGPR<=85 -- spills break the
// hand-counted vmcnt protocol and the inline-asm V loads (rounds 8/9 failure).
__global__ __launch_bounds__(256, 2) void flash_k(
    const __hip_bfloat16* __restrict__ Q,
    const __hip_bfloat16* __restrict__ Kt,
    const __hip_bfloat16* __restrict__ V,
    __hip_bfloat16* __restrict__ part,
    float* __restrict__ cArr,
    float* __restrict__ lArr) {
  __shared__ short Ks[64 * 256];  // 32 KB swizzled K tile
  __shared__ short Ps[64 * 64];   // 8 KB swizzled block-shared P (reused as l[] at end)

  const int tid = threadIdx.x;
  const int w = tid >> 6, l = tid & 63, g = l >> 4, ln = l & 15;
  const int bid = blockIdx.x;
  const int batch = bid & 7;
  const int half = (bid >> 3) & 1;
  const int qb = (bid >> 4) << 6;
  const int kvBase = half << 11;  // 0 or 2048
  const size_t bo = (size_t)batch * (4096 * 256);
  const float CE = 0.09016844005556021f;  // log2(e)/sqrt(256)

  // hoisted LDS addressing (XOR swizzle on byte bits 4-6)
  const int swz45 = (16 * g) ^ ((ln & 3) << 4);
  const int s6 = ((ln >> 2) & 1) << 6;
  const char* Ks0 = (const char*)Ks + (ln * 512 + swz45 + s6);
  const char* Ks1 = Ks0 + (((ln >> 2) & 1) ? -64 : 64);
  const char* Pr0 = (const char*)Ps + (ln * 128 + swz45 + s6);
  const char* Pr1 = Pr0 + (((ln >> 2) & 1) ? -64 : 64);
  const int pwOff = (16 * w + ln) * 128 + 8 * (g & 1) + (((g >> 1) ^ (ln & 1)) << 4) +
                    (((ln >> 1) & 1) << 5) + s6;

  // Q fragments (B-operand): lane ln = q-row (16w+ln), k = 32kk+8g+j
  bf16x8 qf[8];
  {
    const __hip_bfloat16* qp = Q + bo + (size_t)(qb + 16 * w + ln) * 256 + 8 * g;
#pragma unroll
    for (int kk = 0; kk < 8; ++kk) qf[kk] = *(const bf16x8*)(qp + 32 * kk);
  }

  f32x4 acc[4][4];  // [qg][ci]: rows q=16qg+4g+r, cols cv=64w+16ci+ln
#pragma unroll
  for (int qg = 0; qg < 4; ++qg)
#pragma unroll
    for (int ci = 0; ci < 4; ++ci) acc[qg][ci] = (f32x4){0.f, 0.f, 0.f, 0.f};
  float l_run = 0.f;
  float cval = 0.f;  // fixed mhat*CE per q-row (set at t==0)

  // staging lane constants (pre-swizzled global chunks)
  const int kRow = 16 * w + (l >> 5);
  const int kChunk = (l & 31) ^ (l >> 5);
  const short* Kb = (const short*)(Kt + bo);
  const short* Vp = (const short*)(V + bo) + (size_t)(64 * w + ln) * 4096 + 8 * g;

#define SB __builtin_amdgcn_sched_barrier(0)

#define STAGEK(M0)                                                             \
  do {                                                                         \
    _Pragma("unroll") for (int j = 0; j < 8; ++j) {                            \
      const short* gp =                                                        \
          Kb + (size_t)((M0) + kRow + 2 * j) * 256 + 8 * (kChunk ^ ((2 * j) & 7)); \
      gload16(gp, Ks + w * 4096 + j * 512);                                    \
    }                                                                          \
  } while (0)

  STAGEK(kvBase);
  SB;

  for (int t = 0; t < 32; ++t) {
    const int m0 = kvBase + (t << 6);

    // issue V fragment loads for tile t (consumed at PV below)
    bf16x8 vfr[8];
#pragma unroll
    for (int ci = 0; ci < 4; ++ci)
#pragma unroll
      for (int kk = 0; kk < 2; ++kk) {
        const short* gp = Vp + (size_t)ci * (16 * 4096) + (m0 + 32 * kk);
        asm volatile("global_load_dwordx4 %0, %1, off"
                     : "=v"(vfr[2 * ci + kk]) : "v"(gp));
      }
    SB;

    // ---- top barrier: K(t) landed (8 V loads outstanding) ----
    asm volatile("s_waitcnt vmcnt(8)" ::: "memory");
    SB;
    __builtin_amdgcn_s_barrier();
    asm volatile("" ::: "memory");
    SB;

    // QK^T: lane ln = q-row, keys 16mi+4g+r
    f32x4 sf[4];
#pragma unroll
    for (int mi = 0; mi < 4; ++mi) sf[mi] = (f32x4){0.f, 0.f, 0.f, 0.f};
    __builtin_amdgcn_s_setprio(1);
#pragma unroll
    for (int kk = 0; kk < 8; ++kk) {
      const char* kp = ((kk & 1) ? Ks1 : Ks0) + 128 * (kk >> 1);
#pragma unroll
      for (int mi = 0; mi < 4; ++mi) {
        bf16x8 a = *(const bf16x8*)(kp + 8192 * mi);
        sf[mi] = MFMA16(a, qf[kk], sf[mi]);
      }
    }
    __builtin_amdgcn_s_setprio(0);

    // fixed-mhat softmax (per q-row = ln)
    float sv[16];
#pragma unroll
    for (int mi = 0; mi < 4; ++mi)
#pragma unroll
      for (int r = 0; r < 4; ++r) sv[4 * mi + r] = sf[mi][r];
    if (t == 0) {
      float a0 = fmaxf(fmaxf(sv[0], sv[1]), sv[2]);
      float a1 = fmaxf(fmaxf(sv[3], sv[4]), sv[5]);
      float a2 = fmaxf(fmaxf(sv[6], sv[7]), sv[8]);
      float a3 = fmaxf(fmaxf(sv[9], sv[10]), sv[11]);
      float a4 = fmaxf(fmaxf(sv[12], sv[13]), sv[14]);
      float mmax = fmaxf(fmaxf(fmaxf(fmaxf(a0, a1), a2), fmaxf(a3, a4)), sv[15]);
      mmax = fmaxf(mmax, __shfl_xor(mmax, 16));
      mmax = fmaxf(mmax, __shfl_xor(mmax, 32));
      cval = mmax * CE;
    }
    float p[16], psum = 0.f;
#pragma unroll
    for (int j = 0; j < 16; ++j) {
      p[j] = exp2f(fminf(fmaf(sv[j], CE, -cval), 63.0f));
      psum += p[j];
    }
    psum += __shfl_xor(psum, 16);
    psum += __shfl_xor(psum, 32);
    l_run += psum;

    // pack P (bf16) into shared LDS, swizzled; addr(mi) = pwOff ^ (mi<<5)
    {
      uint2 pk0, pk1, pk2, pk3;
      pk0.x = (unsigned)f2bf(p[0])  | ((unsigned)f2bf(p[1])  << 16);
      pk0.y = (unsigned)f2bf(p[2])  | ((unsigned)f2bf(p[3])  << 16);
      pk1.x = (unsigned)f2bf(p[4])  | ((unsigned)f2bf(p[5])  << 16);
      pk1.y = (unsigned)f2bf(p[6])  | ((unsigned)f2bf(p[7])  << 16);
      pk2.x = (unsigned)f2bf(p[8])  | ((unsigned)f2bf(p[9])  << 16);
      pk2.y = (unsigned)f2bf(p[10]) | ((unsigned)f2bf(p[11]) << 16);
      pk3.x = (unsigned)f2bf(p[12]) | ((unsigned)f2bf(p[13]) << 16);
      pk3.y = (unsigned)f2bf(p[14]) | ((unsigned)f2bf(p[15]) << 16);
      char* Pb = (char*)Ps;
      *(uint2*)(Pb + (pwOff ^ 0))  = pk0;
      *(uint2*)(Pb + (pwOff ^ 32)) = pk1;
      *(uint2*)(Pb + (pwOff ^ 64)) = pk2;
      *(uint2*)(Pb + (pwOff ^ 96)) = pk3;
    }

    // ---- barrier B1: P visible; all waves done reading Ks(t) ----
    asm volatile("s_waitcnt lgkmcnt(0)" ::: "memory");
    SB;
    __builtin_amdgcn_s_barrier();
    asm volatile("" ::: "memory");
    SB;

    if (t < 31) {
      STAGEK(m0 + 64);  // K(t+1), flies under PV + softmax(t+1)
      SB;
      asm volatile("s_waitcnt vmcnt(8)" ::: "memory");  // V(t) landed
    } else {
      asm volatile("s_waitcnt vmcnt(0)" ::: "memory");
    }
    SB;

    // PV: acc[qg][ci] += P(q,keys) . V^T(keys,cv)
    __builtin_amdgcn_s_setprio(1);
#pragma unroll
    for (int kk = 0; kk < 2; ++kk) {
#pragma unroll
      for (int qg = 0; qg < 4; ++qg) {
        bf16x8 pa = *(const bf16x8*)((kk ? Pr1 : Pr0) + 2048 * qg);
#pragma unroll
        for (int ci = 0; ci < 4; ++ci)
          acc[qg][ci] = MFMA16(pa, vfr[2 * ci + kk], acc[qg][ci]);
      }
    }
    __builtin_amdgcn_s_setprio(0);
    SB;
  }
#undef STAGEK
#undef SB

  // epilogue: exchange row sums via Ps, write normalized partials + (c,l)
  __syncthreads();
  float* Pf = (float*)Ps;
  if (g == 0) {
    Pf[16 * w + ln] = l_run;
    const int qi = (half * 8 + batch) * 4096 + qb + 16 * w + ln;
    cArr[qi] = cval;
    lArr[qi] = l_run;
  }
  __syncthreads();

  __hip_bfloat16* pb = part + ((size_t)(half * 8 + batch) * 4096 + qb) * 256;
#pragma unroll
  for (int qg = 0; qg < 4; ++qg) {
    f32x4 lv = *(const f32x4*)&Pf[16 * qg + 4 * g];
    f32x4 li;
#pragma unroll
    for (int r = 0; r < 4; ++r) li[r] = 1.0f / lv[r];
#pragma unroll
    for (int ci = 0; ci < 4; ++ci) {
#pragma unroll
      for (int r = 0; r < 4; ++r) {
        float val = acc[qg][ci][r] * li[r];
        pb[(size_t)(16 * qg + 4 * g + r) * 256 + 64 * w + 16 * ci + ln] = __float2bfloat16(val);
      }
    }
  }
}

// merge two normalized halves (non-propagating NaN guards)
__global__ __launch_bounds__(256) void merge_k(
    const __hip_bfloat16* __restrict__ part,
    const float* __restrict__ cArr, const float* __restrict__ lArr,
    __hip_bfloat16* __restrict__ ctx) {
  const int tid = threadIdx.x;
  const int R = blockIdx.x * 8 + (tid >> 5);  // 0..32767 = b*4096+q
  const int cv = (tid & 31) * 8;
  const float c0 = cArr[R], c1 = cArr[32768 + R];
  const float l0 = lArr[R], l1 = lArr[32768 + R];
  const float Cm = fmaxf(c0, c1);
  float w0 = (l0 > 0.f) ? exp2f(c0 - Cm) * l0 : 0.f;
  float w1 = (l1 > 0.f) ? exp2f(c1 - Cm) * l1 : 0.f;
  const float sum = w0 + w1;
  const float inv = sum > 0.f ? 1.0f / sum : 0.f;
  w0 *= inv;
  w1 *= inv;
  const short* p0 = (const short*)part + (size_t)R * 256 + cv;
  const short* p1 = p0 + (size_t)32768 * 256;
  bf16x8 a0 = *(const bf16x8*)p0;
  bf16x8 a1 = *(const bf16x8*)p1;
  bf16x8 o;
#pragma unroll
  for (int j = 0; j < 8; ++j) {
    float v0 = (w0 > 0.f) ? w0 * bf2f(a0[j]) : 0.f;
    float v1 = (w1 > 0.f) ? w1 * bf2f(a1[j]) : 0.f;
    o[j] = (short)f2bf(v0 + v1);
  }
  *(bf16x8*)((short*)ctx + (size_t)R * 256 + cv) = o;
}

// ---------------- host launcher ----------------

extern "C" void kernel_launch(void* const* d_in, const int* in_sizes, int n_in,
                              void* d_out, int out_size, void* d_ws, size_t ws_size,
                              hipStream_t stream) {
  const float* x   = (const float*)d_in[0];
  const float* kW1 = (const float*)d_in[1];
  const float* kG1 = (const float*)d_in[2];
  const float* kB1 = (const float*)d_in[3];
  const float* kM1 = (const float*)d_in[4];
  const float* kV1 = (const float*)d_in[5];
  const float* kW2 = (const float*)d_in[6];
  const float* kG2 = (const float*)d_in[7];
  const float* kB2 = (const float*)d_in[8];
  const float* kM2 = (const float*)d_in[9];
  const float* kV2 = (const float*)d_in[10];
  const float* qW1 = (const float*)d_in[11];
  const float* qG1 = (const float*)d_in[12];
  const float* qB1 = (const float*)d_in[13];
  const float* qM1 = (const float*)d_in[14];
  const float* qV1 = (const float*)d_in[15];
  const float* qW2 = (const float*)d_in[16];
  const float* qG2 = (const float*)d_in[17];
  const float* qB2 = (const float*)d_in[18];
  const float* qM2 = (const float*)d_in[19];
  const float* qV2 = (const float*)d_in[20];
  const float* vW  = (const float*)d_in[21];
  const float* wW  = (const float*)d_in[22];
  const float* wG  = (const float*)d_in[23];
  const float* wB  = (const float*)d_in[24];
  const float* wM  = (const float*)d_in[25];
  const float* wV  = (const float*)d_in[26];

  char* ws = (char*)d_ws;
  __hip_bfloat16* bQW1 = (__hip_bfloat16*)(ws + 0);
  __hip_bfloat16* bKW1 = (__hip_bfloat16*)(ws + 262144);
  __hip_bfloat16* bQW2 = (__hip_bfloat16*)(ws + 524288);
  __hip_bfloat16* bKW2 = (__hip_bfloat16*)(ws + 655360);
  __hip_bfloat16* bVW  = (__hip_bfloat16*)(ws + 786432);
  __hip_bfloat16* bWW  = (__hip_bfloat16*)(ws + 1048576);
  float* bnBase = (float*)(ws + 1310720);
  float* sQ1 = bnBase + 0;
  float* tQ1 = bnBase + 256;
  float* sQ2 = bnBase + 512;
  float* tQ2 = bnBase + 768;
  float* sK1 = bnBase + 1024;
  float* tK1 = bnBase + 1280;
  float* sK2 = bnBase + 1536;
  float* tK2 = bnBase + 1792;
  float* sWo = bnBase + 2048;
  float* tWo = bnBase + 2560;
  float* cArr = (float*)(ws + 1572864);                      // 256 KB, ends 1835008
  float* lArr = (float*)(ws + 1835008);                      // 256 KB, ends 2097152
  __hip_bfloat16* xT   = (__hip_bfloat16*)(ws + 2097152);    // 32 MB (reused as flash partials)
  __hip_bfloat16* bufA = (__hip_bfloat16*)(ws + 35651584);   // 16 MB (q1 / k1 / ctx)
  __hip_bfloat16* q2b  = (__hip_bfloat16*)(ws + 52428800);   // 16 MB
  __hip_bfloat16* k2b  = (__hip_bfloat16*)(ws + 69206016);   // 16 MB
  __hip_bfloat16* vB   = (__hip_bfloat16*)(ws + 85983232);   // 16 MB

  conv_w_k<<<2560, 256, 0, stream>>>(qW1, kW1, qW2, kW2, vW, wW, bQW1);
  bn_all_k<<<6, 256, 0, stream>>>(qG1, qB1, qM1, qV1, qG2, qB2, qM2, qV2,
                                  kG1, kB1, kM1, kV1, kG2, kB2, kM2, kV2,
                                  wG, wB, wM, wV, bnBase);

  transpose_k<<<dim3(64, 8, 8), dim3(64, 4), 0, stream>>>(x, xT);

  // q1 = CBR(xT . qW1^T)
  gemm_nt_k<1><<<dim3(32, 2, 8), 256, 0, stream>>>(xT, 2097152L, bQW1, 0L, bufA, 1048576L,
                                                   512, 512, 256, 512, sQ1, tQ1);
  // q2 = CBR(q1 . qW2^T)
  gemm_nt_k<1><<<dim3(32, 2, 8), 256, 0, stream>>>(bufA, 1048576L, bQW2, 0L, q2b, 1048576L,
                                                   256, 256, 256, 256, sQ2, tQ2);
  // k1
  gemm_nt_k<1><<<dim3(32, 2, 8), 256, 0, stream>>>(xT, 2097152L, bKW1, 0L, bufA, 1048576L,
                                                   512, 512, 256, 512, sK1, tK1);
  // k2
  gemm_nt_k<1><<<dim3(32, 2, 8), 256, 0, stream>>>(bufA, 1048576L, bKW2, 0L, k2b, 1048576L,
                                                   256, 256, 256, 256, sK2, tK2);
  // v = vW . x -> (256 x 4096 per batch)
  gemm_nt_k<0><<<dim3(2, 32, 8), 256, 0, stream>>>(bVW, 0L, xT, 2097152L, vB, 1048576L,
                                                   512, 512, 4096, 512, nullptr, nullptr);
  // flash attention (split-K x2): partials into xT region (xT is dead now)
  flash_k<<<1024, 256, 0, stream>>>(q2b, k2b, vB, xT, cArr, lArr);
  // merge halves -> ctx in bufA
  merge_k<<<4096, 256, 0, stream>>>(xT, cArr, lArr, bufA);
  // out = CBR_row(wW . ctx^T) -> d_out (fp32)
  gemm_nt_k<2><<<dim3(4, 32, 8), 256, 0, stream>>>(bWW, 0L, bufA, 1048576L, d_out, 2097152L,
                                                   256, 256, 4096, 256, sWo, tWo);
}